// Round 7
// baseline (143.558 us; speedup 1.0000x reference)
//
#include <hip/hip_runtime.h>
#include <cmath>

typedef __attribute__((ext_vector_type(8))) short short8;
typedef __attribute__((ext_vector_type(4))) float f32x4;

static __device__ __forceinline__ unsigned short f2bf(float f) {
    unsigned u = __float_as_uint(f);
    unsigned r = (u + 0x7fffu + ((u >> 16) & 1u)) >> 16;
    return (unsigned short)r;
}
static __device__ __forceinline__ float bf2f(unsigned short h) {
    return __uint_as_float(((unsigned)h) << 16);
}
// fast 3-way split: levels 1-2 truncated, level 3 RNE; v = s1+s2+s3 + O(2^-25 |v|)
static __device__ __forceinline__ void split3(float v, short& o1, short& o2, short& o3) {
    unsigned u1 = __float_as_uint(v) & 0xffff0000u;
    float r1 = v - __uint_as_float(u1);
    unsigned u2 = __float_as_uint(r1) & 0xffff0000u;
    float r2 = r1 - __uint_as_float(u2);
    o1 = (short)(u1 >> 16);
    o2 = (short)(u2 >> 16);
    o3 = (short)f2bf(r2);
}

#define PH 1048576   // h plane elems (16384*64)
#define PB 131072    // emb/W plane elems (2048*64)

// ---------------- prep: zero wacc + inv-norms + excitability bonus ----------
// global order: [qk 0..511][fv 512..767][q 768..1279][k(rel) 1280..1791][val 1792..2047]
__global__ void prep_kernel(const float* __restrict__ emb,
                            const float* __restrict__ emb_rel_k,
                            const float* __restrict__ ema_qk,
                            const float* __restrict__ ema_v,
                            const float* __restrict__ ema_rel,
                            const float* __restrict__ ema_val,
                            float* __restrict__ invn,
                            float* __restrict__ bonus,
                            float* __restrict__ wacc)
{
    int n = blockIdx.x * 64 + threadIdx.x;   // 32 x 64 -> 2048
    {
        float4 z = {0.f, 0.f, 0.f, 0.f};
        *(float4*)(wacc + (size_t)n * 8)     = z;
        *(float4*)(wacc + (size_t)n * 8 + 4) = z;
    }
    const float* row;
    float ema;
    if (n < 512)       { row = emb + (size_t)n * 64;                ema = ema_qk[n]; }
    else if (n < 768)  { row = emb + (size_t)n * 64;                ema = ema_v[n - 512]; }
    else if (n < 1280) { row = emb + (size_t)n * 64;                ema = ema_rel[n - 768]; }
    else if (n < 1792) { row = emb_rel_k + (size_t)(n - 1280) * 64; ema = ema_rel[n - 1280]; }
    else               { row = emb + (size_t)(n - 512) * 64;        ema = ema_val[n - 1792]; }
    float s = 0.f;
    #pragma unroll
    for (int k = 0; k < 64; k += 4) {
        float4 v = *(const float4*)(row + k);
        s += v.x*v.x + v.y*v.y + v.z*v.z + v.w*v.w;
    }
    invn[n] = 1.0f / sqrtf(s);
    float ex = 1.0f - ema * (1.0f / 1.5f);   // TAU = 1.5
    ex = fminf(fmaxf(ex, 0.f), 1.f);
    bonus[n] = ex * 1.0f;                    // EXC_W = 1.0
}

// ---------------- pack W into 3 bf16 split planes, MFMA B-fragment order ----
// plane: [ksg 0..63][t 0..3][lane 0..63][j 0..7]; col=16t+(l&15), k=ksg*32+(l>>4)*8+j
__global__ void wtpack3_kernel(const float* __restrict__ proj_w, unsigned short* __restrict__ wp)
{
    int idx = blockIdx.x * 256 + threadIdx.x;   // 16384
    int l = idx & 63;
    int t = (idx >> 6) & 3;
    int ksg = idx >> 8;
    int col = t * 16 + (l & 15);
    int kb = ksg * 32 + (l >> 4) * 8;
    float4 w0 = *(const float4*)(proj_w + (size_t)col * 2048 + kb);
    float4 w1 = *(const float4*)(proj_w + (size_t)col * 2048 + kb + 4);
    float v[8] = {w0.x, w0.y, w0.z, w0.w, w1.x, w1.y, w1.z, w1.w};
    short8 s1, s2, s3;
    #pragma unroll
    for (int j = 0; j < 8; ++j) {
        short a, b, c; split3(v[j], a, b, c);
        s1[j] = a; s2[j] = b; s3[j] = c;
    }
    size_t base = (size_t)ksg * 2048 + t * 512 + l * 8;
    *(short8*)(wp + base)          = s1;
    *(short8*)(wp + PB + base)     = s2;
    *(short8*)(wp + 2 * PB + base) = s3;
}

// ---------------- pack emb (global order) into 3 bf16 B-frag planes ---------
// plane: [nt 0..127][ks 0..1][lane][j]; neuron=nt*16+(l&15), k=ks*32+(l>>4)*8+j
__global__ void embpack_kernel(const float* __restrict__ emb,
                               const float* __restrict__ emb_rel_k,
                               unsigned short* __restrict__ bp)
{
    int idx = blockIdx.x * 256 + threadIdx.x;   // 16384
    int l = idx & 63;
    int ks = (idx >> 6) & 1;
    int nt = idx >> 7;
    int n = nt * 16 + (l & 15);
    const float* src;
    if (n < 1280)      src = emb + (size_t)n * 64;
    else if (n < 1792) src = emb_rel_k + (size_t)(n - 1280) * 64;
    else               src = emb + (size_t)(n - 512) * 64;
    int c0 = ks * 32 + (l >> 4) * 8;
    float4 w0 = *(const float4*)(src + c0);
    float4 w1 = *(const float4*)(src + c0 + 4);
    float v[8] = {w0.x, w0.y, w0.z, w0.w, w1.x, w1.y, w1.z, w1.w};
    short8 s1, s2, s3;
    #pragma unroll
    for (int j = 0; j < 8; ++j) {
        short a, b, c; split3(v[j], a, b, c);
        s1[j] = a; s2[j] = b; s3[j] = c;
    }
    size_t base = ((size_t)nt * 2 + ks) * 512 + l * 8;
    *(short8*)(bp + base)          = s1;
    *(short8*)(bp + PB + base)     = s2;
    *(short8*)(bp + 2 * PB + base) = s3;
}

#define MFMA16(a, b, c) __builtin_amdgcn_mfma_f32_16x16x32_bf16(a, b, c, 0, 0, 0)

// ---------------- proj GEMM via split-bf16 MFMA, LDS-staged A ---------------
// Block: 32 rows, 8 waves K-split (wave covers 256 K = 8 k-steps of 32).
// Per step: A slab [32 rows][128 B] staged densely into wave-private LDS
// (double-buffered, no barriers); row stride 36 floats -> 2-way-free ds_read.
// Epilogue: LDS-reduce 8 partials + bias, emit h as 3 bf16 A-frag planes.
__launch_bounds__(512)
__global__ void proj_kernel(const float* __restrict__ x,
                            const unsigned short* __restrict__ wp,
                            const float* __restrict__ proj_b,
                            unsigned short* __restrict__ hs)
{
    extern __shared__ __align__(16) float sbuf[];   // 18432 floats = 72 KB
    // staging: [wave][2][32*36]; epilogue alias: [8][2048]

    const int tid = threadIdx.x;
    const int wave = tid >> 6, lane = tid & 63;
    const int g_ = lane >> 4, r_ = lane & 15;
    const int srow = lane >> 3;            // staging: 8 rows per instr
    const int scol = (lane & 7) * 4;       // staging: float offset 0..28
    const int row0 = blockIdx.x * 32;
    const int wbase = wave * 2304;         // 2 bufs * 1152 floats

    f32x4 acc[2][4];
    #pragma unroll
    for (int rt = 0; rt < 2; ++rt)
        #pragma unroll
        for (int t = 0; t < 4; ++t) acc[rt][t] = (f32x4){0.f, 0.f, 0.f, 0.f};

    // prologue: stage k-step 0 into buf 0 (dense: 4 x dwordx4, 8 rows each)
    {
        float4 pr[4];
        #pragma unroll
        for (int p = 0; p < 4; ++p)
            pr[p] = *(const float4*)(x + (size_t)(row0 + p * 8 + srow) * 2048 + wave * 256 + scol);
        #pragma unroll
        for (int p = 0; p < 4; ++p)
            *(float4*)(&sbuf[wbase + (p * 8 + srow) * 36 + scol]) = pr[p];
    }
    int cur = 0;

    for (int ks = 0; ks < 8; ++ks) {
        const int ksg = wave * 8 + ks;
        // B fragments first (L2-hot, coalesced 16B/lane) so MFMAs need only vmcnt(4)
        const unsigned short* wb = wp + (size_t)ksg * 2048 + lane * 8;
        short8 B1[4], B2[4], B3[4];
        #pragma unroll
        for (int t = 0; t < 4; ++t) {
            B1[t] = *(const short8*)(wb + t * 512);
            B2[t] = *(const short8*)(wb + PB + t * 512);
            B3[t] = *(const short8*)(wb + 2 * PB + t * 512);
        }
        // issue A prefetch for next k-step (HBM latency hides under MFMAs)
        float4 pr[4];
        if (ks < 7) {
            #pragma unroll
            for (int p = 0; p < 4; ++p)
                pr[p] = *(const float4*)(x + (size_t)(row0 + p * 8 + srow) * 2048
                                           + wave * 256 + (ks + 1) * 32 + scol);
        }
        // A fragments from LDS (2-way-free ds_read_b128)
        const float* ab = &sbuf[wbase + cur * 1152];
        float4 a00 = *(const float4*)(ab + r_ * 36 + g_ * 8);
        float4 a01 = *(const float4*)(ab + r_ * 36 + g_ * 8 + 4);
        float4 a10 = *(const float4*)(ab + (16 + r_) * 36 + g_ * 8);
        float4 a11 = *(const float4*)(ab + (16 + r_) * 36 + g_ * 8 + 4);

        float av0[8] = {a00.x, a00.y, a00.z, a00.w, a01.x, a01.y, a01.z, a01.w};
        float av1[8] = {a10.x, a10.y, a10.z, a10.w, a11.x, a11.y, a11.z, a11.w};
        short8 A1[2], A2[2], A3[2];
        #pragma unroll
        for (int j = 0; j < 8; ++j) {
            short t1, t2, t3;
            split3(av0[j], t1, t2, t3); A1[0][j] = t1; A2[0][j] = t2; A3[0][j] = t3;
            split3(av1[j], t1, t2, t3); A1[1][j] = t1; A2[1][j] = t2; A3[1][j] = t3;
        }
        #pragma unroll
        for (int rt = 0; rt < 2; ++rt)
            #pragma unroll
            for (int t = 0; t < 4; ++t) {
                acc[rt][t] = MFMA16(A1[rt], B1[t], acc[rt][t]);
                acc[rt][t] = MFMA16(A1[rt], B2[t], acc[rt][t]);
                acc[rt][t] = MFMA16(A2[rt], B1[t], acc[rt][t]);
                acc[rt][t] = MFMA16(A2[rt], B2[t], acc[rt][t]);
                acc[rt][t] = MFMA16(A1[rt], B3[t], acc[rt][t]);
                acc[rt][t] = MFMA16(A3[rt], B1[t], acc[rt][t]);
            }
        // land the prefetch in the other buffer (wave-private; no barrier)
        if (ks < 7) {
            float* db = &sbuf[wbase + (cur ^ 1) * 1152];
            #pragma unroll
            for (int p = 0; p < 4; ++p)
                *(float4*)(db + (p * 8 + srow) * 36 + scol) = pr[p];
            cur ^= 1;
        }
    }

    __syncthreads();   // staging regions now reusable as partial buffer

    // D: row = g*4+rr (within 16-tile), col = t*16 + r_
    #pragma unroll
    for (int rt = 0; rt < 2; ++rt)
        #pragma unroll
        for (int t = 0; t < 4; ++t)
            #pragma unroll
            for (int rr = 0; rr < 4; ++rr)
                sbuf[wave * 2048 + (rt * 16 + g_ * 4 + rr) * 64 + t * 16 + r_] = acc[rt][t][rr];
    __syncthreads();

    // reduce 8 K-partials + bias -> sbuf[0..2047]; each thread owns 4 elems
    {
        int i0 = tid * 4;
        float4 s = *(const float4*)(&sbuf[i0]);
        #pragma unroll
        for (int w = 1; w < 8; ++w) {
            float4 p = *(const float4*)(&sbuf[w * 2048 + i0]);
            s.x += p.x; s.y += p.y; s.z += p.z; s.w += p.w;
        }
        float4 bb = *(const float4*)(proj_b + (i0 & 63));
        s.x += bb.x; s.y += bb.y; s.z += bb.z; s.w += bb.w;
        *(float4*)(&sbuf[i0]) = s;
    }
    __syncthreads();

    // pack h tile into 3 A-frag planes (256 threads: 2 rt x 2 ks x 64 lanes)
    if (tid < 256) {
        int pl = tid & 63;
        int ks = (tid >> 6) & 1;
        int rt = tid >> 7;
        int row = rt * 16 + (pl & 15);
        int c0 = ks * 32 + (pl >> 4) * 8;
        const float* hb = &sbuf[row * 64 + c0];
        short8 s1, s2, s3;
        #pragma unroll
        for (int j = 0; j < 8; ++j) {
            short a, b, c; split3(hb[j], a, b, c);
            s1[j] = a; s2[j] = b; s3[j] = c;
        }
        size_t rg = (size_t)blockIdx.x * 2 + rt;
        size_t base = (rg * 2 + ks) * 512 + pl * 8;
        *(short8*)(hs + base)          = s1;
        *(short8*)(hs + PH + base)     = s2;
        *(short8*)(hs + 2 * PH + base) = s3;
    }
}

// ---------------- routing via MFMA: logits -> segment softmax -> pool -------
// Block: 32 rows, 8 waves; wave w owns neurons [w*256, w*256+256).
// Segments align to waves: 0-1=qk, 2=fv, 3-4=q, 5-6=k, 7=val.
__launch_bounds__(512)
__global__ void route_kernel(const unsigned short* __restrict__ hs,
                             const unsigned short* __restrict__ bp,
                             const float* __restrict__ imp,
                             const float* __restrict__ invn_g,
                             const float* __restrict__ bonus_g,
                             float* __restrict__ wout)
{
    __shared__ float2 red[32][8];

    const int tid = threadIdx.x;
    const int wave = tid >> 6, lane = tid & 63;
    const int g_ = lane >> 4, r_ = lane & 15;
    const int rowBase = blockIdx.x * 32;
    const int b = rowBase >> 11;
    const int n0 = wave * 256;

    // A-fragments for both 16-row tiles, both k-halves, 3 splits
    short8 A1[2][2], A2[2][2], A3[2][2];
    #pragma unroll
    for (int rt = 0; rt < 2; ++rt)
        #pragma unroll
        for (int ks = 0; ks < 2; ++ks) {
            size_t base = ((size_t)(blockIdx.x * 2 + rt) * 2 + ks) * 512 + lane * 8;
            A1[rt][ks] = *(const short8*)(hs + base);
            A2[rt][ks] = *(const short8*)(hs + PH + base);
            A3[rt][ks] = *(const short8*)(hs + 2 * PH + base);
        }

    f32x4 acc[2][16];
    #pragma unroll
    for (int rt = 0; rt < 2; ++rt)
        #pragma unroll
        for (int t = 0; t < 16; ++t) acc[rt][t] = (f32x4){0.f, 0.f, 0.f, 0.f};

    #pragma unroll
    for (int t = 0; t < 16; ++t) {
        const int nt = wave * 16 + t;
        #pragma unroll
        for (int ks = 0; ks < 2; ++ks) {
            size_t base = ((size_t)nt * 2 + ks) * 512 + lane * 8;
            short8 B1 = *(const short8*)(bp + base);
            short8 B2 = *(const short8*)(bp + PB + base);
            short8 B3 = *(const short8*)(bp + 2 * PB + base);
            #pragma unroll
            for (int rt = 0; rt < 2; ++rt) {
                acc[rt][t] = MFMA16(A1[rt][ks], B1, acc[rt][t]);
                acc[rt][t] = MFMA16(A1[rt][ks], B2, acc[rt][t]);
                acc[rt][t] = MFMA16(A2[rt][ks], B1, acc[rt][t]);
                acc[rt][t] = MFMA16(A2[rt][ks], B2, acc[rt][t]);
                acc[rt][t] = MFMA16(A1[rt][ks], B3, acc[rt][t]);
                acc[rt][t] = MFMA16(A3[rt][ks], B1, acc[rt][t]);
            }
        }
    }

    float inv_[16], bon_[16];
    #pragma unroll
    for (int t = 0; t < 16; ++t) {
        inv_[t] = invn_g[n0 + t * 16 + r_];
        bon_[t] = bonus_g[n0 + t * 16 + r_];
    }

    // pass 1: per (rt,r) row -> wave-local (max, expsum) -> LDS
    float m_[2][4], s_[2][4];
    #pragma unroll
    for (int rt = 0; rt < 2; ++rt)
        #pragma unroll
        for (int r = 0; r < 4; ++r) {
            float m = -INFINITY;
            float lv[16];
            #pragma unroll
            for (int t = 0; t < 16; ++t) {
                lv[t] = fmaf(acc[rt][t][r], inv_[t], bon_[t]);
                m = fmaxf(m, lv[t]);
            }
            #pragma unroll
            for (int d = 1; d <= 8; d <<= 1)
                m = fmaxf(m, __shfl_xor(m, d));
            float s = 0.f;
            #pragma unroll
            for (int t = 0; t < 16; ++t) s += __expf(lv[t] - m);
            #pragma unroll
            for (int d = 1; d <= 8; d <<= 1)
                s += __shfl_xor(s, d);
            m_[rt][r] = m; s_[rt][r] = s;
            if (r_ == 0) red[rt * 16 + g_ * 4 + r][wave] = make_float2(m, s);
        }
    __syncthreads();

    // pass 2: cross-wave combine, recompute P, weighted pool
    const unsigned PTAB = 0xF5634F01u;
    const int pn = (PTAB >> (wave * 4)) & 0xF;
    float accw[16];
    #pragma unroll
    for (int t = 0; t < 16; ++t) accw[t] = 0.f;

    #pragma unroll
    for (int rt = 0; rt < 2; ++rt)
        #pragma unroll
        for (int r = 0; r < 4; ++r) {
            const int row = rt * 16 + g_ * 4 + r;
            float m = m_[rt][r], s = s_[rt][r];
            float M = m, Z = s;
            if (pn != 0xF) {
                float2 q = red[row][pn];
                M = fmaxf(m, q.x);
                Z = s * __expf(m - M) + q.y * __expf(q.x - M);
            }
            float coef = imp[rowBase + row] / Z * __expf(m - M);
            #pragma unroll
            for (int t = 0; t < 16; ++t)
                accw[t] = fmaf(coef, __expf(fmaf(acc[rt][t][r], inv_[t], bon_[t]) - m), accw[t]);
        }

    // reduce the 4 g-groups (rows) per column, then write
    #pragma unroll
    for (int t = 0; t < 16; ++t) {
        accw[t] += __shfl_xor(accw[t], 16);
        accw[t] += __shfl_xor(accw[t], 32);
    }
    #pragma unroll
    for (int tt = 0; tt < 4; ++tt) {
        int t = g_ * 4 + tt;
        float v = (tt == 0) ? accw[g_ * 4] : (tt == 1) ? accw[g_ * 4 + 1]
                : (tt == 2) ? accw[g_ * 4 + 2] : accw[g_ * 4 + 3];
        atomicAdd(&wout[b * 2048 + n0 + t * 16 + r_], v);
    }
}

// ---------------- top-k + softmax + sorted indices, one wave per (b,route) --
__global__ void topk_kernel(const float* __restrict__ w, float* __restrict__ out)
{
    const int lane = threadIdx.x;
    const int blk = blockIdx.x;          // 0..39
    const int b = blk / 5;
    const int route = blk % 5;

    const int segoff[5] = {0, 512, 768, 1280, 1792};
    const int seglen[5] = {512, 256, 512, 512, 256};
    const int kk[5]     = {64, 32, 64, 64, 32};
    const int soff[5]   = {0, 64, 96, 160, 224};
    const int ibase[5]  = {2048, 2560, 2816, 3328, 3840};

    const int L = seglen[route];
    const int K = kk[route];
    const int nv = L >> 6;               // 4 or 8 values per lane

    float v[8];
    #pragma unroll
    for (int i = 0; i < 8; ++i) {
        v[i] = -INFINITY;
        if (i < nv) v[i] = w[b * 2048 + segoff[route] + lane + 64 * i];
    }

    float selv = 0.f; int seli = 0;
    for (int it = 0; it < K; ++it) {
        float bv = -INFINITY; int bi = 0x7fffffff;
        #pragma unroll
        for (int i = 0; i < 8; ++i) {
            int li = lane + 64 * i;
            if (v[i] > bv || (v[i] == bv && li < bi)) { bv = v[i]; bi = li; }
        }
        for (int d = 1; d < 64; d <<= 1) {
            float ov = __shfl_xor(bv, d);
            int   oi = __shfl_xor(bi, d);
            if (ov > bv || (ov == bv && oi < bi)) { bv = ov; bi = oi; }
        }
        if (lane == it) { selv = bv; seli = bi; }
        #pragma unroll
        for (int i = 0; i < 8; ++i)
            if ((bi >> 6) == i && (bi & 63) == lane) v[i] = -INFINITY;
    }

    float m = __shfl(selv, 0);
    float e = (lane < K) ? __expf(selv - m) : 0.f;
    float s = e;
    for (int d = 1; d < 64; d <<= 1) s += __shfl_xor(s, d);
    if (lane < K) out[b * 256 + soff[route] + lane] = e / s;

    int rank = 0;
    for (int j = 0; j < K; ++j) {
        int oj = __shfl(seli, j);
        if (oj < seli) rank++;
    }
    if (lane < K) out[ibase[route] + b * K + rank] = (float)seli;
}

extern "C" void kernel_launch(void* const* d_in, const int* in_sizes, int n_in,
                              void* d_out, int out_size, void* d_ws, size_t ws_size,
                              hipStream_t stream)
{
    const float* x        = (const float*)d_in[0];
    const float* imp      = (const float*)d_in[1];
    const float* proj_w   = (const float*)d_in[2];
    const float* proj_b   = (const float*)d_in[3];
    const float* emb      = (const float*)d_in[4];
    const float* emb_rel  = (const float*)d_in[5];
    const float* ema_qk   = (const float*)d_in[6];
    const float* ema_v    = (const float*)d_in[7];
    const float* ema_rel  = (const float*)d_in[8];
    const float* ema_val  = (const float*)d_in[9];
    float* out = (float*)d_out;

    float* invn  = (float*)d_ws;                       // 2048 f32
    float* bonus = invn + 2048;                        // 2048 f32
    float* wacc  = bonus + 2048;                       // 16384 f32
    unsigned short* wp = (unsigned short*)(wacc + 16384);  // 3*PB u16
    unsigned short* bp = wp + 3 * PB;                  // 3*PB u16
    unsigned short* hs = bp + 3 * PB;                  // 3*PH u16 (6 MB)

    prep_kernel<<<32, 64, 0, stream>>>(emb, emb_rel, ema_qk, ema_v, ema_rel, ema_val, invn, bonus, wacc);
    wtpack3_kernel<<<64, 256, 0, stream>>>(proj_w, wp);
    embpack_kernel<<<64, 256, 0, stream>>>(emb, emb_rel, bp);
    proj_kernel<<<512, 512, 73728, stream>>>(x, wp, proj_b, hs);
    route_kernel<<<512, 512, 0, stream>>>(hs, bp, imp, invn, bonus, wacc);
    topk_kernel<<<40, 64, 0, stream>>>(wacc, out);
}